// Round 13
// baseline (668.778 us; speedup 1.0000x reference)
//
#include <hip/hip_runtime.h>
#include <stdint.h>

typedef unsigned short u16;
typedef __attribute__((ext_vector_type(8))) short bfrag;   // 8 x bf16 (4 VGPRs)
typedef __attribute__((ext_vector_type(4))) short bfrag4;  // 4 x bf16 (2 VGPRs)
typedef __attribute__((ext_vector_type(4))) float f32x4;   // MFMA C/D

#define MFMA_BF16 __builtin_amdgcn_mfma_f32_16x16x32_bf16

static constexpr int Bc = 2;      // batch
static constexpr int Tc = 2048;   // seq
static constexpr int Cc = 1024;   // channels
static constexpr int Hc = 16;     // heads
static constexpr int Dc = 64;     // head dim
static constexpr int N2 = 2 * Cc; // 2048, packed QK row length
static constexpr int NBLK = 512;  // persistent grid: co-resident under ANY
                                  // VGPR<=256 (launch_bounds 2/EU) + LDS 34.8KB

__device__ __forceinline__ u16 f2bf(float f) {
    union { unsigned int i; float f; } v; v.f = f;
    unsigned int u = v.i;
    u += 0x7fffu + ((u >> 16) & 1u);   // round-to-nearest-even
    return (u16)(u >> 16);
}
__device__ __forceinline__ unsigned int fbits(float f) {
    union { unsigned int i; float f; } v; v.f = f; return v.i;
}
// pack two f32 -> two bf16 (truncation) in ONE v_perm_b32: {hi.bf16, lo.bf16}
__device__ __forceinline__ unsigned int pack_bf2(float hi, float lo) {
    return __builtin_amdgcn_perm(fbits(hi), fbits(lo), 0x07060302u);
}

// K=16 MFMA for PV (S^T C-layout == B-operand layout)
#if __has_builtin(__builtin_amdgcn_mfma_f32_16x16x16bf16_1k)
__device__ __forceinline__ f32x4 MFMA16(bfrag4 a, bfrag4 b, f32x4 c) {
    return __builtin_amdgcn_mfma_f32_16x16x16bf16_1k(a, b, c, 0, 0, 0);
}
#elif __has_builtin(__builtin_amdgcn_mfma_f32_16x16x16_bf16)
__device__ __forceinline__ f32x4 MFMA16(bfrag4 a, bfrag4 b, f32x4 c) {
    return __builtin_amdgcn_mfma_f32_16x16x16_bf16(a, b, c, 0, 0, 0);
}
#else
__device__ __forceinline__ f32x4 MFMA16(bfrag4 a, bfrag4 b, f32x4 c) {
    bfrag a8 = {a[0], a[1], a[2], a[3], 0, 0, 0, 0};
    bfrag b8 = {b[0], b[1], b[2], b[3], 0, 0, 0, 0};
    return MFMA_BF16(a8, b8, c, 0, 0, 0);
}
#endif

// async global -> LDS, 16B per lane; deposits at lds + lane*16.
__device__ __forceinline__ void async_load16(const u16* g, u16* lds) {
    __builtin_amdgcn_global_load_lds(
        (const __attribute__((address_space(1))) unsigned int*)g,
        (__attribute__((address_space(3))) unsigned int*)lds, 16, 0, 0);
}

// ---------------------------------------------------------------------------
// SYSTEM-scope software grid barrier (monotone counter, no reset, no ABA).
// Release side: __threadfence_system + SYSTEM-scope RMW -> full L2 writeback.
// Acquire side: SYSTEM-scope acquire load -> L1/L2 invalidate.
// Timeout break = fail loudly (wrong result) instead of hanging.
// ---------------------------------------------------------------------------
__device__ __forceinline__ void grid_barrier(unsigned int* bar, unsigned int target) {
    __syncthreads();
    if (threadIdx.x == 0) {
        __threadfence_system();
        __hip_atomic_fetch_add(bar, 1u, __ATOMIC_RELEASE,
                               __HIP_MEMORY_SCOPE_SYSTEM);
        long long t0 = clock64();
        while (__hip_atomic_load(bar, __ATOMIC_ACQUIRE,
                                 __HIP_MEMORY_SCOPE_SYSTEM) < target) {
            __builtin_amdgcn_s_sleep(2);
            if (clock64() - t0 > 3000000000LL) break;   // ~1.2s escape hatch
        }
        __threadfence_system();
    }
    __syncthreads();
}

// Dynamic work ticket: block-uniform grab via LDS broadcast.
__device__ __forceinline__ int grab(unsigned int* tk, int* s_slot) {
    __syncthreads();
    if (threadIdx.x == 0)
        *s_slot = (int)__hip_atomic_fetch_add(tk, 1u, __ATOMIC_RELAXED,
                                              __HIP_MEMORY_SCOPE_AGENT);
    __syncthreads();
    return *s_slot;
}

// ---------------------------------------------------------------------------
// Phase bodies (proven correct in R11's eager cooperative run).
// ---------------------------------------------------------------------------

__device__ __forceinline__ void prep_body(
    int blk, int nblk, const float* __restrict__ x,
    const float* __restrict__ w_qkv, const float* __restrict__ w_out,
    u16* __restrict__ xb, u16* __restrict__ WqkvT, u16* __restrict__ WoutT,
    u16* tile) {
    const int tid = threadIdx.x;
    const int nthr = nblk * 256;
    for (int i = blk * 256 + tid; i < 1048576; i += nthr) {   // 1M float4
        const float4 v = *(const float4*)(x + (size_t)i * 4);
        ushort4 o;
        o.x = f2bf(v.x); o.y = f2bf(v.y); o.z = f2bf(v.z); o.w = f2bf(v.w);
        *(ushort4*)(xb + (size_t)i * 4) = o;
    }
    const int tx = tid & 31, ty = tid >> 5;   // 32 x 8
    for (int tau = blk; tau < 4096; tau += nblk) {
        const float* in; u16* outp; int rows, cols, c0, r0;
        if (tau < 3072) {
            in = w_qkv; outp = WqkvT; rows = 1024; cols = 3072;
            c0 = (tau % 96) * 32; r0 = (tau / 96) * 32;
        } else {
            const int t2 = tau - 3072;
            in = w_out; outp = WoutT; rows = 1024; cols = 1024;
            c0 = (t2 & 31) * 32; r0 = (t2 >> 5) * 32;
        }
        __syncthreads();   // tile reuse across loop iterations
        for (int i = 0; i < 4; i++)
            tile[(ty + 8 * i) * 33 + tx] =
                f2bf(in[(size_t)(r0 + ty + 8 * i) * cols + c0 + tx]);
        __syncthreads();
        for (int i = 0; i < 4; i++)
            outp[(size_t)(c0 + ty + 8 * i) * rows + r0 + tx] =
                tile[tx * 33 + ty + 8 * i];
    }
}

// GEMM tile, double-buffered single-barrier BK=32 K-loop.
// smem elems: A0 @0, A1 @4096, B0 @8192, B1 @12288; MODE1 V-epilogue 128x136.
template <int MODE>
__device__ __forceinline__ void gemm_body(
    int bx, int by, const u16* __restrict__ A, const u16* __restrict__ BT,
    const float* __restrict__ bias, void* __restrict__ out_p,
    u16* __restrict__ Vt, int M, int Nn, int K, u16* smem) {
    const int tid  = threadIdx.x;
    const int wave = tid >> 6, lane = tid & 63;
    const int quad = lane >> 4, l16 = lane & 15;
    const int wm = wave & 1, wn = wave >> 1;
    const int m0 = by * 128, n0 = bx * 128;

    __syncthreads();   // LDS handoff from previous phase/tile

    f32x4 acc[4][4];
    #pragma unroll
    for (int i = 0; i < 4; i++)
        #pragma unroll
        for (int j = 0; j < 4; j++)
            acc[i][j] = (f32x4){0.f, 0.f, 0.f, 0.f};

    const int rloc = 2 * (lane >> 3) + ((lane >> 2) & 1);
    const int cg_  = ((lane & 3) ^ ((lane >> 3) & 3)) * 8;
    const int rk   = (l16 >> 1) & 3;
    const int rodd = (l16 & 1) * 32;

    const int T = K >> 5;
    #define STAGE(t, bsel)                                                      \
        {                                                                       \
            const int k0_ = (t) << 5;                                           \
            const int ao_ = (bsel) * 4096;                                      \
            _Pragma("unroll")                                                   \
            for (int j = 0; j < 2; j++) {                                       \
                const int R0 = wave * 32 + j * 16;                              \
                async_load16(A  + (size_t)(m0 + R0 + rloc) * K + k0_ + cg_,     \
                             smem + ao_ + R0 * 32);                             \
                async_load16(BT + (size_t)(n0 + R0 + rloc) * K + k0_ + cg_,     \
                             smem + 8192 + ao_ + R0 * 32);                      \
            }                                                                   \
        }

    STAGE(0, 0);
    for (int t = 0; t < T; t++) {
        __syncthreads();
        if (t + 1 < T) STAGE(t + 1, (t + 1) & 1);
        const u16* Ab = smem + (t & 1) * 4096;
        const u16* Bb = smem + 8192 + (t & 1) * 4096;
        bfrag af[4], bf[4];
        #pragma unroll
        for (int mt = 0; mt < 4; mt++) {
            const int r = wm * 64 + mt * 16 + l16;
            af[mt] = *(const bfrag*)(Ab + (r >> 1) * 64 + rodd + (quad ^ rk) * 8);
        }
        #pragma unroll
        for (int nt = 0; nt < 4; nt++) {
            const int r = wn * 64 + nt * 16 + l16;
            bf[nt] = *(const bfrag*)(Bb + (r >> 1) * 64 + rodd + (quad ^ rk) * 8);
        }
        #pragma unroll
        for (int mt = 0; mt < 4; mt++)
            #pragma unroll
            for (int nt = 0; nt < 4; nt++)
                acc[mt][nt] = MFMA_BF16(af[mt], bf[nt], acc[mt][nt], 0, 0, 0);
    }
    #undef STAGE

    if (MODE == 1 && n0 >= 2048) {
        __syncthreads();
        #pragma unroll
        for (int nt = 0; nt < 4; nt++) {
            const int ln = wn * 64 + nt * 16 + l16;
            const float bv = bias[n0 + ln];
            u16* col = smem + ln * 136;
            #pragma unroll
            for (int mt = 0; mt < 4; mt++) {
                const int lmb = wm * 64 + mt * 16 + quad * 4;
                #pragma unroll
                for (int r = 0; r < 4; r++)
                    col[lmb + r] = f2bf(acc[mt][nt][r] + bv);
            }
        }
        __syncthreads();
        const int bb = m0 >> 11, t0 = m0 & 2047;
        const int h0 = (n0 - 2048) >> 6;
        const int dl = tid >> 1;
        const int th = (tid & 1) * 64;
        u16* dst = Vt + ((size_t)(bb * Hc + h0 + (dl >> 6)) * Dc + (dl & 63)) * Tc
                      + t0 + th;
        const u16* srcr = smem + dl * 136 + th;
        #pragma unroll
        for (int c = 0; c < 8; c++)
            *(uint4*)(dst + c * 8) = *(const uint4*)(srcr + c * 8);
    } else {
        #pragma unroll
        for (int nt = 0; nt < 4; nt++) {
            const int gn = n0 + wn * 64 + nt * 16 + l16;
            const float bv = bias[gn];
            #pragma unroll
            for (int mt = 0; mt < 4; mt++) {
                #pragma unroll
                for (int r = 0; r < 4; r++) {
                    const int gm = m0 + wm * 64 + mt * 16 + quad * 4 + r;
                    if (MODE == 1)
                        ((u16*)out_p)[(size_t)gm * Nn + gn] = f2bf(acc[mt][nt][r] + bv);
                    else
                        ((float*)out_p)[(size_t)gm * Nn + gn] = acc[mt][nt][r] + bv;
                }
            }
        }
    }
}

// attention tile tau (bh = tau&31, jq = 31-(tau>>5)); ticket order = LPT.
// smem elems: K0 @0, K1 @4096, V0 @8192, V1 @12288.
__device__ __forceinline__ void attn_body(
    int tau, const u16* __restrict__ QKp, const u16* __restrict__ Vt,
    u16* __restrict__ Ob, u16* smem) {
    const int tid  = threadIdx.x;
    const int wave = tid >> 6, lane = tid & 63;
    const int quad = lane >> 4, l16 = lane & 15;

    const int bh = tau & 31;
    const int jq = 31 - (tau >> 5);
    const int b = bh >> 4, h = bh & 15;
    const u16* Qp = QKp + (size_t)b * Tc * N2 + h * Dc;
    const u16* Kp = Qp + Cc;
    const u16* Vp = Vt + (size_t)bh * Dc * Tc;

    const int qw = jq * 64 + wave * 16;

    const int row8 = lane >> 3;
    const int swz  = ((lane & 7) ^ row8) * 8;
    const int pk0 = ((quad)     ^ (l16 & 7)) * 8;
    const int pk1 = ((quad + 4) ^ (l16 & 7)) * 8;

    __syncthreads();   // LDS handoff

    bfrag qf0, qf1;
    {
        const u16* qp = Qp + (size_t)(qw + l16) * N2 + quad * 8;
        qf0 = *(const bfrag*)qp;
        qf1 = *(const bfrag*)(qp + 32);
    }

    float l_i = 0.f;
    f32x4 oacc[4];
    #pragma unroll
    for (int g = 0; g < 4; g++) oacc[g] = (f32x4){0.f, 0.f, 0.f, 0.f};

    #define STAGEKV(t, bsel)                                                    \
        {                                                                       \
            const int k0_ = (t) * 64;                                           \
            const int o_ = (bsel) * 4096;                                       \
            _Pragma("unroll")                                                   \
            for (int j = 0; j < 2; j++) {                                       \
                const int rr = wave * 16 + j * 8;                               \
                const int gr = rr + row8;                                       \
                async_load16(Kp + (size_t)(k0_ + gr) * N2 + swz,                \
                             smem + o_ + rr * 64);                              \
                async_load16(Vp + (size_t)gr * Tc + k0_ + swz,                  \
                             smem + 8192 + o_ + rr * 64);                       \
            }                                                                   \
        }

    STAGEKV(0, 0);
    for (int t = 0; t <= jq; t++) {
        __syncthreads();
        if (t < jq) STAGEKV(t + 1, (t + 1) & 1);
        const u16* Kb = smem + (t & 1) * 4096;
        const u16* Vb = smem + 8192 + (t & 1) * 4096;

        f32x4 s[4];
        #pragma unroll
        for (int g = 0; g < 4; g++) {
            const u16* kb = Kb + (g * 16 + l16) * 64;
            bfrag kf0 = *(const bfrag*)(kb + pk0);
            bfrag kf1 = *(const bfrag*)(kb + pk1);
            f32x4 z = (f32x4){0.f, 0.f, 0.f, 0.f};
            z = MFMA_BF16(kf0, qf0, z, 0, 0, 0);
            z = MFMA_BF16(kf1, qf1, z, 0, 0, 0);
            s[g] = z;
        }

        #pragma unroll
        for (int g = 0; g < 4; g++)
            #pragma unroll
            for (int r = 0; r < 4; r++)
                s[g][r] = __expf(s[g][r] * 0.125f);
        if (t == jq) {
            #pragma unroll
            for (int g = 0; g < 4; g++)
                #pragma unroll
                for (int r = 0; r < 4; r++)
                    if (g * 16 + quad * 4 + r > wave * 16 + l16) s[g][r] = 0.f;
        }
        #pragma unroll
        for (int g = 0; g < 4; g++)
            l_i += s[g][0] + s[g][1] + s[g][2] + s[g][3];

        #pragma unroll
        for (int g = 0; g < 4; g++) {
            union { unsigned int u[2]; bfrag4 v; } pf;
            pf.u[0] = pack_bf2(s[g][1], s[g][0]);
            pf.u[1] = pack_bf2(s[g][3], s[g][2]);
            const int vc = ((2 * g + (quad >> 1)) ^ (l16 & 7)) * 8 + (quad & 1) * 4;
            #pragma unroll
            for (int ng = 0; ng < 4; ng++) {
                const bfrag4 vf = *(const bfrag4*)(Vb + (ng * 16 + l16) * 64 + vc);
                oacc[ng] = MFMA16(vf, pf.v, oacc[ng]);
            }
        }
    }
    #undef STAGEKV

    float rs = l_i;
    rs += __shfl_xor(rs, 16);
    rs += __shfl_xor(rs, 32);
    const float inv = 1.f / rs;
    const int q = qw + l16;
    u16* orow = Ob + (size_t)(b * Tc + q) * Cc + h * Dc + quad * 4;
    #pragma unroll
    for (int ng = 0; ng < 4; ng++) {
        ushort4 o;
        o.x = f2bf(oacc[ng][0] * inv);
        o.y = f2bf(oacc[ng][1] * inv);
        o.z = f2bf(oacc[ng][2] * inv);
        o.w = f2bf(oacc[ng][3] * inv);
        *(ushort4*)(orow + ng * 16) = o;
    }
}

// ---------------------------------------------------------------------------
// Persistent megakernel, 512 blocks (co-residency guaranteed: LDS 34.8KB->4/CU,
// launch_bounds(256,2)->VGPR<=256->>=2/CU => capacity >= 512). Phases separated
// by SYSTEM-scope grid barriers; work distributed by atomic tickets (ctr[1..3]).
// ---------------------------------------------------------------------------
__global__ __launch_bounds__(256, 2) void mega(
    const float* __restrict__ x, const float* __restrict__ w_qkv,
    const float* __restrict__ b_qkv, const float* __restrict__ w_out,
    const float* __restrict__ b_out, float* __restrict__ out,
    u16* __restrict__ xb, u16* __restrict__ WqkvT, u16* __restrict__ WoutT,
    u16* __restrict__ QKp, u16* __restrict__ Vt, u16* __restrict__ Ao,
    unsigned int* __restrict__ ctr) {
    __shared__ __align__(16) u16 smem[17408];   // 34816 B union
    __shared__ int s_slot;
    unsigned int* bar = ctr;

    prep_body(blockIdx.x, NBLK, x, w_qkv, w_out, xb, WqkvT, WoutT, smem);
    grid_barrier(bar, NBLK);

    for (;;) {                                   // gemm1: 768 tiles, dynamic
        const int t = grab(ctr + 1, &s_slot);
        if (t >= 768) break;
        gemm_body<1>(t % 24, t / 24, xb, WqkvT, b_qkv, QKp, Vt,
                     4096, 2048, 1024, smem);
    }
    grid_barrier(bar, 2 * NBLK);

    for (;;) {                                   // attn: 1024 tiles, LPT order
        const int t = grab(ctr + 2, &s_slot);
        if (t >= 1024) break;
        attn_body(t, QKp, Vt, Ao, smem);
    }
    grid_barrier(bar, 3 * NBLK);

    for (;;) {                                   // gemm2: 256 tiles, dynamic
        const int t = grab(ctr + 3, &s_slot);
        if (t >= 256) break;
        gemm_body<0>(t & 7, t >> 3, Ao, WoutT, b_out, out, nullptr,
                     4096, 1024, 1024, smem);
    }
}

// ---------------------------------------------------------------------------
extern "C" void kernel_launch(void* const* d_in, const int* in_sizes, int n_in,
                              void* d_out, int out_size, void* d_ws, size_t ws_size,
                              hipStream_t stream) {
    const float* x     = (const float*)d_in[0];   // [B*T][C] fp32
    const float* w_qkv = (const float*)d_in[1];   // [C][3C] fp32
    const float* b_qkv = (const float*)d_in[2];   // [3C] fp32
    const float* w_out = (const float*)d_in[3];   // [C][C] fp32
    const float* b_out = (const float*)d_in[4];   // [C] fp32
    float* out = (float*)d_out;                   // [B*T][C] fp32
    u16* ws  = (u16*)d_ws;

    u16* xb    = ws;                               // [4096][1024] bf16 (x)
    u16* WqkvT = xb    + (size_t)4096 * 1024;      // [3072][1024]
    u16* WoutT = WqkvT + (size_t)3072 * 1024;      // [1024][1024]
    u16* QKp   = WoutT + (size_t)1024 * 1024;      // [4096][2048] packed Q,K
    u16* Vt    = QKp   + (size_t)4096 * 2048;      // [B*H][D][T]
    u16* Ao    = xb;                               // alias: xb consumed by GEMM1
    unsigned int* ctr = (unsigned int*)(ws + (size_t)24 * 1024 * 1024); // @48MB

    hipMemsetAsync(ctr, 0, 16, stream);            // bar + 3 tickets := 0
    mega<<<NBLK, 256, 0, stream>>>(x, w_qkv, b_qkv, w_out, b_out, out,
                                   xb, WqkvT, WoutT, QKp, Vt, Ao, ctr);
}